// Round 7
// baseline (1462.586 us; speedup 1.0000x reference)
//
#include <hip/hip_runtime.h>
#include <hip/hip_bf16.h>

#define EPSV 1e-5f
#define CHUNK 64    // dst nodes per bucket (bucket = dst >> 6)
#define LROW 68     // padded floats per node in agg LDS accumulator
#define MAXNB 2048  // supports N <= 131072

typedef __attribute__((ext_vector_type(8))) short bf16x8;
typedef __attribute__((ext_vector_type(4))) float f32x4;

__device__ __forceinline__ ushort f2bf(float f) {
    union { float f; unsigned u; } c; c.f = f;
    unsigned u = c.u;
    return (ushort)((u + 0x7fffu + ((u >> 16) & 1u)) >> 16);
}
__device__ __forceinline__ float bf2f(ushort h) {
    union { unsigned u; float f; } c; c.u = ((unsigned)h) << 16;
    return c.f;
}

// ---------- bucketed CSR build ----------
// pack: low 20 bits = src (N < 2^20), bits 20..25 = dst & 63

__global__ void bucket_hist(const int* __restrict__ ei, int* __restrict__ bcnt, int E, int NB) {
    __shared__ int h[MAXNB];
    for (int b = threadIdx.x; b < NB; b += 256) h[b] = 0;
    __syncthreads();
    int stride = gridDim.x * 256;
    for (int e = blockIdx.x * 256 + threadIdx.x; e < E; e += stride)
        atomicAdd(&h[ei[E + e] >> 6], 1);
    __syncthreads();
    for (int b = threadIdx.x; b < NB; b += 256)
        if (h[b]) atomicAdd(&bcnt[b], h[b]);
}

// scan over buckets (2 per thread) + W pre-swizzle (fused; both tiny)
__global__ void bucket_scan(const int* __restrict__ bcnt, int* __restrict__ bbase,
                            int* __restrict__ bcur, int NB,
                            const float* __restrict__ W1, const float* __restrict__ W2,
                            ushort* __restrict__ wsw1, ushort* __restrict__ wsw2) {
    __shared__ int sd[1024];
    int t = threadIdx.x;
    int b0 = 2 * t, b1 = 2 * t + 1;
    int c0 = (b0 < NB) ? bcnt[b0] : 0;
    int c1 = (b1 < NB) ? bcnt[b1] : 0;
    int v = c0 + c1;
    sd[t] = v;
    __syncthreads();
    for (int off = 1; off < 1024; off <<= 1) {
        int x = (t >= off) ? sd[t - off] : 0;
        __syncthreads();
        sd[t] += x;
        __syncthreads();
    }
    int excl = sd[t] - v;
    if (b0 < NB) { bbase[b0] = excl; bcur[b0] = excl; }
    if (b1 < NB) { bbase[b1] = excl + c0; bcur[b1] = excl + c0; }
    if (t == 1023) bbase[NB] = sd[1023];
    // W pre-swizzle into MFMA B-fragment order: (k,n) -> [((k>>3)*64+n)*8+(k&7)]
    for (int i = t; i < 128 * 64; i += 1024) {
        int k = i >> 6, n = i & 63;
        wsw1[((k >> 3) * 64 + n) * 8 + (k & 7)] = f2bf(W1[i]);
    }
    for (int i = t; i < 64 * 64; i += 1024) {
        int k = i >> 6, n = i & 63;
        wsw2[((k >> 3) * 64 + n) * 8 + (k & 7)] = f2bf(W2[i]);
    }
}

#define EPB 8192  // edges per bucket_scatter block

__global__ void __launch_bounds__(256) bucket_scatter(const int* __restrict__ ei,
                                                      int* __restrict__ bcur,
                                                      unsigned* __restrict__ bdata, int E,
                                                      int NB) {
    __shared__ int h[MAXNB];
    __shared__ int cur[MAXNB];
    int base = blockIdx.x * EPB;
    int end = min(base + EPB, E);
    for (int b = threadIdx.x; b < NB; b += 256) h[b] = 0;
    __syncthreads();
    for (int e = base + threadIdx.x; e < end; e += 256)
        atomicAdd(&h[ei[E + e] >> 6], 1);
    __syncthreads();
    for (int b = threadIdx.x; b < NB; b += 256) {
        int c = h[b];
        cur[b] = c ? atomicAdd(&bcur[b], c) : 0;
    }
    __syncthreads();
    for (int e = base + threadIdx.x; e < end; e += 256) {
        int s = ei[e], d = ei[E + e];
        int pos = atomicAdd(&cur[d >> 6], 1);
        bdata[pos] = (unsigned)s | ((unsigned)(d & (CHUNK - 1)) << 20);
    }
}

// per-bucket degree -> dinv (no scan / scatter needed anymore)
__global__ void __launch_bounds__(256) fine_hist(const unsigned* __restrict__ bdata,
                                                 const int* __restrict__ bbase,
                                                 float* __restrict__ dinv, int N) {
    __shared__ int h[CHUNK];
    int t = threadIdx.x;
    if (t < CHUNK) h[t] = 0;
    __syncthreads();
    int beg = bbase[blockIdx.x], end = bbase[blockIdx.x + 1];
    for (int e = beg + t; e < end; e += 256) atomicAdd(&h[(bdata[e] >> 20) & 63], 1);
    __syncthreads();
    int node = blockIdx.x * CHUNK + t;
    if (t < CHUNK && node < N) dinv[node] = rsqrtf((float)h[t] + 1.0f);
}

// ---------- matmul1: Ht[N,64](bf16) = dinv[r] * (X[N,128](fp32) @ W1) ----------

__global__ void __launch_bounds__(256) mm1_kernel(const float* __restrict__ X,
                                                  const ushort* __restrict__ wsw,
                                                  const float* __restrict__ dinv,
                                                  ushort* __restrict__ Ht, int N) {
    const int KO = 4;
    int w = threadIdx.x >> 6, lane = threadIdx.x & 63;
    int m = lane & 15, q = lane >> 4;
    int row = blockIdx.x * 64 + w * 16 + m;

    bf16x8 afrag[KO];
#pragma unroll
    for (int kk = 0; kk < KO; kk++) {
        float xv[8];
        if (row < N) {
            const float4* xp = reinterpret_cast<const float4*>(X + (size_t)row * 128 + kk * 32 + q * 8);
            float4 v0 = xp[0], v1 = xp[1];
            xv[0] = v0.x; xv[1] = v0.y; xv[2] = v0.z; xv[3] = v0.w;
            xv[4] = v1.x; xv[5] = v1.y; xv[6] = v1.z; xv[7] = v1.w;
        } else {
#pragma unroll
            for (int j = 0; j < 8; j++) xv[j] = 0.f;
        }
#pragma unroll
        for (int j = 0; j < 8; j++) afrag[kk][j] = (short)f2bf(xv[j]);
    }

    float dv[4];
#pragma unroll
    for (int reg = 0; reg < 4; reg++) {
        int r = blockIdx.x * 64 + w * 16 + q * 4 + reg;
        dv[reg] = (r < N) ? dinv[r] : 0.f;
    }

    const bf16x8* wp = reinterpret_cast<const bf16x8*>(wsw);
#pragma unroll
    for (int ct = 0; ct < 4; ct++) {
        f32x4 acc = {0.f, 0.f, 0.f, 0.f};
#pragma unroll
        for (int kk = 0; kk < KO; kk++) {
            bf16x8 b = wp[(kk * 4 + q) * 64 + ct * 16 + m];
            acc = __builtin_amdgcn_mfma_f32_16x16x32_bf16(afrag[kk], b, acc, 0, 0, 0);
        }
#pragma unroll
        for (int reg = 0; reg < 4; reg++) {
            int r = blockIdx.x * 64 + w * 16 + q * 4 + reg;
            if (r < N) Ht[(size_t)r * 64 + ct * 16 + m] = f2bf(acc[reg] * dv[reg]);
        }
    }
}

// ---------- matmul2: fused GraphNorm+LayerNorm on A, then Ht2 = dinv * (norm(A) @ W2) ----------

__global__ void __launch_bounds__(256) mm2_kernel(
    const ushort* __restrict__ A2, const ushort* __restrict__ wsw,
    const float* __restrict__ sums, const float* __restrict__ gn_w,
    const float* __restrict__ gn_b, const float* __restrict__ gn_ms,
    const float* __restrict__ ln_w, const float* __restrict__ ln_b,
    const float* __restrict__ dinv, ushort* __restrict__ Ht, int N) {
    __shared__ float sg[64], tg[64], lwv[64], lbv[64];
    int t = threadIdx.x;
    if (t < 64) {
        float invN = 1.0f / (float)N;
        float mean = sums[t] * invN;
        float m2 = sums[64 + t] * invN;
        float ms = gn_ms[t];
        float var = m2 - 2.f * ms * mean * mean + ms * ms * mean * mean;
        float s = gn_w[t] * rsqrtf(var + EPSV);
        sg[t] = s;
        tg[t] = gn_b[t] - s * ms * mean;
        lwv[t] = ln_w[t];
        lbv[t] = ln_b[t];
    }
    __syncthreads();

    int w = t >> 6, lane = t & 63;
    int m = lane & 15, q = lane >> 4;
    int row = blockIdx.x * 64 + w * 16 + m;

    float g[16];
#pragma unroll
    for (int kk = 0; kk < 2; kk++) {
        uint4 u = make_uint4(0, 0, 0, 0);
        if (row < N)
            u = *reinterpret_cast<const uint4*>(A2 + (size_t)row * 64 + kk * 32 + q * 8);
        unsigned uu[4] = {u.x, u.y, u.z, u.w};
#pragma unroll
        for (int p = 0; p < 4; p++) {
            int f0 = kk * 32 + q * 8 + 2 * p;
            g[kk * 8 + 2 * p] = sg[f0] * bf2f((ushort)uu[p]) + tg[f0];
            g[kk * 8 + 2 * p + 1] = sg[f0 + 1] * bf2f((ushort)(uu[p] >> 16)) + tg[f0 + 1];
        }
    }
    float s1 = 0.f;
#pragma unroll
    for (int i = 0; i < 16; i++) s1 += g[i];
    s1 += __shfl_xor(s1, 16);
    s1 += __shfl_xor(s1, 32);
    float mu = s1 * (1.f / 64.f);
    float s2 = 0.f;
#pragma unroll
    for (int i = 0; i < 16; i++) {
        float c = g[i] - mu;
        s2 += c * c;
    }
    s2 += __shfl_xor(s2, 16);
    s2 += __shfl_xor(s2, 32);
    float rs = rsqrtf(s2 * (1.f / 64.f) + EPSV);

    bf16x8 afrag[2];
#pragma unroll
    for (int kk = 0; kk < 2; kk++) {
#pragma unroll
        for (int j = 0; j < 8; j++) {
            int f = kk * 32 + q * 8 + j;
            float y = lwv[f] * (g[kk * 8 + j] - mu) * rs + lbv[f];
            afrag[kk][j] = (short)f2bf(y);
        }
    }

    float dv[4];
#pragma unroll
    for (int reg = 0; reg < 4; reg++) {
        int r = blockIdx.x * 64 + w * 16 + q * 4 + reg;
        dv[reg] = (r < N) ? dinv[r] : 0.f;
    }

    const bf16x8* wp = reinterpret_cast<const bf16x8*>(wsw);
#pragma unroll
    for (int ct = 0; ct < 4; ct++) {
        f32x4 acc = {0.f, 0.f, 0.f, 0.f};
#pragma unroll
        for (int kk = 0; kk < 2; kk++) {
            bf16x8 b = wp[(kk * 4 + q) * 64 + ct * 16 + m];
            acc = __builtin_amdgcn_mfma_f32_16x16x32_bf16(afrag[kk], b, acc, 0, 0, 0);
        }
#pragma unroll
        for (int reg = 0; reg < 4; reg++) {
            int r = blockIdx.x * 64 + w * 16 + q * 4 + reg;
            if (r < N) Ht[(size_t)r * 64 + ct * 16 + m] = f2bf(acc[reg] * dv[reg]);
        }
    }
}

// ---------- edge aggregation v5: bucket-LDS accumulate (dense gather stream) ----------
// block = bucket of 64 dst nodes; consumes bdata directly (src | dloc<<20).
// LDS acc layout: feature f of node d at acc[d*LROW + 16*(f&3) + (f>>2)] ->
// lane fq writes its 4 features at base d*LROW+fq with ds offsets {0,16,32,48} floats.
// Sentinel entry = N: gathers zero row Ht[N], adds 0 to local node 0 (harmless).

__global__ void __launch_bounds__(256) agg_lds(
    const ushort* __restrict__ Ht, const unsigned* __restrict__ bdata,
    const int* __restrict__ bbase, const float* __restrict__ dinv,
    const float* __restrict__ bias, ushort* __restrict__ out,
    float* __restrict__ sums, int N) {
    __shared__ float acc[CHUNK * LROW];
    __shared__ float ls[128];   // colstats: s1[0:64), s2[64:128)
    __shared__ float sbias[64];
    int t = threadIdx.x;
    int lane = t & 63;
    int g = lane >> 4, fq = lane & 15;
    int w = t >> 6;

    for (int i = t; i < CHUNK * LROW; i += 256) acc[i] = 0.f;
    if (t < 128) ls[t] = 0.f;
    if (t < 64) sbias[t] = bias[t];
    __syncthreads();

    int beg = bbase[blockIdx.x], end = bbase[blockIdx.x + 1];
    const uint2* H2 = reinterpret_cast<const uint2*>(Ht);
    const unsigned SENT = (unsigned)N;

    for (int o = beg + w * 64; o < end; o += 256) {
        int bn = end - o;
        if (bn > 64) bn = 64;
        unsigned pv = (lane < bn) ? bdata[o + lane] : SENT;
        for (int kb = 0; kb < bn; kb += 16) {  // bn wave-uniform; shfls converged
            int e = kb + g;
            unsigned p0 = __shfl((int)pv, e);
            unsigned p1 = __shfl((int)pv, e + 4);
            unsigned p2 = __shfl((int)pv, e + 8);
            unsigned p3 = __shfl((int)pv, e + 12);
            uint2 u0 = H2[((p0 & 0xFFFFFu) << 4) + fq];
            uint2 u1 = H2[((p1 & 0xFFFFFu) << 4) + fq];
            uint2 u2 = H2[((p2 & 0xFFFFFu) << 4) + fq];
            uint2 u3 = H2[((p3 & 0xFFFFFu) << 4) + fq];
            float* a0 = &acc[((p0 >> 20) & 63) * LROW + fq];
            float* a1 = &acc[((p1 >> 20) & 63) * LROW + fq];
            float* a2 = &acc[((p2 >> 20) & 63) * LROW + fq];
            float* a3 = &acc[((p3 >> 20) & 63) * LROW + fq];
            atomicAdd(a0 + 0, bf2f((ushort)u0.x));
            atomicAdd(a0 + 16, bf2f((ushort)(u0.x >> 16)));
            atomicAdd(a0 + 32, bf2f((ushort)u0.y));
            atomicAdd(a0 + 48, bf2f((ushort)(u0.y >> 16)));
            atomicAdd(a1 + 0, bf2f((ushort)u1.x));
            atomicAdd(a1 + 16, bf2f((ushort)(u1.x >> 16)));
            atomicAdd(a1 + 32, bf2f((ushort)u1.y));
            atomicAdd(a1 + 48, bf2f((ushort)(u1.y >> 16)));
            atomicAdd(a2 + 0, bf2f((ushort)u2.x));
            atomicAdd(a2 + 16, bf2f((ushort)(u2.x >> 16)));
            atomicAdd(a2 + 32, bf2f((ushort)u2.y));
            atomicAdd(a2 + 48, bf2f((ushort)(u2.y >> 16)));
            atomicAdd(a3 + 0, bf2f((ushort)u3.x));
            atomicAdd(a3 + 16, bf2f((ushort)(u3.x >> 16)));
            atomicAdd(a3 + 32, bf2f((ushort)u3.y));
            atomicAdd(a3 + 48, bf2f((ushort)(u3.y >> 16)));
        }
    }
    __syncthreads();

    // writeback: 4 threads per node; thread (d=t>>2, q4=t&3) handles features q4*16..+15
    int d = t >> 2, q4 = t & 3;
    int node = blockIdx.x * CHUNK + d;
    float vv[16];
#pragma unroll
    for (int j = 0; j < 16; j++) vv[j] = 0.f;
    if (node < N) {
        float di = dinv[node];
        const uint2* selfp = H2 + (size_t)node * 16 + q4 * 4;
        uint2* O2 = reinterpret_cast<uint2*>(out) + (size_t)node * 16 + q4 * 4;
#pragma unroll
        for (int k2 = 0; k2 < 4; k2++) {
            uint2 us = selfp[k2];
            float sf[4] = {bf2f((ushort)us.x), bf2f((ushort)(us.x >> 16)),
                           bf2f((ushort)us.y), bf2f((ushort)(us.y >> 16))};
#pragma unroll
            for (int c = 0; c < 4; c++) {
                int f = q4 * 16 + k2 * 4 + c;
                float a = acc[d * LROW + 16 * (f & 3) + (f >> 2)];
                vv[k2 * 4 + c] = fmaxf(di * a + di * sf[c] + sbias[f], 0.f);
            }
            uint2 o;
            o.x = (unsigned)f2bf(vv[k2 * 4 + 0]) | ((unsigned)f2bf(vv[k2 * 4 + 1]) << 16);
            o.y = (unsigned)f2bf(vv[k2 * 4 + 2]) | ((unsigned)f2bf(vv[k2 * 4 + 3]) << 16);
            O2[k2] = o;
        }
    }
    // colstats: shfl-reduce over the wave's 16 nodes (lanes stride 4), then LDS adds
#pragma unroll
    for (int j = 0; j < 16; j++) {
        float a = vv[j];
        float b = a * a;
        a += __shfl_xor(a, 4);  b += __shfl_xor(b, 4);
        a += __shfl_xor(a, 8);  b += __shfl_xor(b, 8);
        a += __shfl_xor(a, 16); b += __shfl_xor(b, 16);
        a += __shfl_xor(a, 32); b += __shfl_xor(b, 32);
        if ((lane >> 2) == 0) {
            int f = q4 * 16 + j;
            atomicAdd(&ls[f], a);
            atomicAdd(&ls[64 + f], b);
        }
    }
    __syncthreads();
    if (t < 128) atomicAdd(&sums[t], ls[t]);
}

// ---------- layer-2 norms + max-pool ----------

__device__ __forceinline__ float gn_ln_row(float x, float mean, float var, float ms, float gw,
                                           float gb, float lw, float lb) {
    float g = gw * (x - ms * mean) * rsqrtf(var + EPSV) + gb;
    float mu = g;
#pragma unroll
    for (int off = 32; off; off >>= 1) mu += __shfl_xor(mu, off);
    mu *= (1.f / 64.f);
    float c = g - mu;
    float vv = c * c;
#pragma unroll
    for (int off = 32; off; off >>= 1) vv += __shfl_xor(vv, off);
    vv *= (1.f / 64.f);
    return lw * c * rsqrtf(vv + EPSV) + lb;
}

__device__ __forceinline__ unsigned fkey(float f) {
    unsigned u = __float_as_uint(f);
    return (u & 0x80000000u) ? ~u : (u | 0x80000000u);
}

__global__ void gnlnmax_kernel(const ushort* __restrict__ A, const float* __restrict__ sums,
                               const float* __restrict__ gn_w, const float* __restrict__ gn_b,
                               const float* __restrict__ gn_ms, const float* __restrict__ ln_w,
                               const float* __restrict__ ln_b, unsigned* __restrict__ pooled,
                               int N) {
    __shared__ float lmax[256];
    int lane = threadIdx.x & 63;
    int wave0 = (blockIdx.x * blockDim.x + threadIdx.x) >> 6;
    int nw = (gridDim.x * blockDim.x) >> 6;
    float invN = 1.0f / (float)N;
    float mean = sums[lane] * invN;
    float m2 = sums[64 + lane] * invN;
    float ms = gn_ms[lane];
    float var = m2 - 2.f * ms * mean * mean + ms * ms * mean * mean;
    float gw = gn_w[lane], gb = gn_b[lane], lw = ln_w[lane], lb = ln_b[lane];
    float mx = -3.4e38f;
    for (int i = wave0; i < N; i += nw) {
        float y = gn_ln_row(bf2f(A[(size_t)i * 64 + lane]), mean, var, ms, gw, gb, lw, lb);
        mx = fmaxf(mx, y);
    }
    lmax[threadIdx.x] = mx;
    __syncthreads();
    if (threadIdx.x < 64) {
        float m = fmaxf(fmaxf(lmax[threadIdx.x], lmax[threadIdx.x + 64]),
                        fmaxf(lmax[threadIdx.x + 128], lmax[threadIdx.x + 192]));
        atomicMax(&pooled[threadIdx.x], fkey(m));
    }
}

// ---------- final FC ----------

__global__ void final_kernel(const unsigned* __restrict__ pooled, const float* __restrict__ fc_W,
                             const float* __restrict__ fc_b, float* __restrict__ out) {
    __shared__ float p[64];
    int t = threadIdx.x;
    if (t < 64) {
        unsigned u = pooled[t];
        p[t] = (u & 0x80000000u) ? __uint_as_float(u ^ 0x80000000u) : __uint_as_float(~u);
    }
    __syncthreads();
    if (t < 32) {
        float acc = fc_b[t];
#pragma unroll
        for (int f = 0; f < 64; f++) acc += p[f] * fc_W[f * 32 + t];
        out[t] = acc;
    }
}

// ---------- launch ----------

static inline size_t align_up(size_t v, size_t a) { return (v + a - 1) & ~(a - 1); }

extern "C" void kernel_launch(void* const* d_in, const int* in_sizes, int n_in, void* d_out,
                              int out_size, void* d_ws, size_t ws_size, hipStream_t stream) {
    const float* x = (const float*)d_in[0];
    const int* ei = (const int*)d_in[1];
    const float* W1 = (const float*)d_in[2];
    const float* b1 = (const float*)d_in[3];
    const float* W2 = (const float*)d_in[4];
    const float* b2 = (const float*)d_in[5];
    const float* gn_w = (const float*)d_in[6];
    const float* gn_b = (const float*)d_in[7];
    const float* gn_ms = (const float*)d_in[8];
    const float* ln_w = (const float*)d_in[9];
    const float* ln_b = (const float*)d_in[10];
    const float* fc_W = (const float*)d_in[11];
    const float* fc_b = (const float*)d_in[12];
    float* out = (float*)d_out;

    const int N = in_sizes[0] / 128;
    const int E = in_sizes[1] / 2;
    const int NB = (N + CHUNK - 1) / CHUNK;

    char* ws = (char*)d_ws;
    size_t off = 0;
    auto alloc = [&](size_t bytes) {
        char* p = ws + off;
        off = align_up(off + bytes, 256);
        return p;
    };
    int* bbase = (int*)alloc((size_t)(NB + 1) * 4);
    int* bcur = (int*)alloc((size_t)(NB + 1) * 4);
    float* dinv = (float*)alloc((size_t)N * 4);
    unsigned* bdata = (unsigned*)alloc((size_t)E * 4);
    ushort* bufB = (ushort*)alloc((size_t)N * 64 * 2);
    ushort* wsw1 = (ushort*)alloc(128 * 64 * 2);
    ushort* wsw2 = (ushort*)alloc(64 * 64 * 2);
    ushort* bufA = (ushort*)alloc((size_t)N * 64 * 2);  // gather source; zero row follows
    // ---- single contiguous zero-init region: [zrow][bcnt][sums][pooled] ----
    size_t zoff = off;
    ushort* zrow = (ushort*)alloc(128);  // bufA row N (contiguous with bufA)
    int* bcnt = (int*)alloc((size_t)(NB + 1) * 4);
    float* sums = (float*)alloc(256 * 4);
    unsigned* pooled = (unsigned*)alloc(64 * 4);
    size_t zlen = off - zoff;
    (void)zrow;

    hipMemsetAsync(ws + zoff, 0, zlen, stream);

    // CSR build (bucketed; no per-node scan/scatter)
    int nbB = (E + EPB - 1) / EPB;
    bucket_hist<<<256, 256, 0, stream>>>(ei, bcnt, E, NB);
    bucket_scan<<<1, 1024, 0, stream>>>(bcnt, bbase, bcur, NB, W1, W2, wsw1, wsw2);
    bucket_scatter<<<nbB, 256, 0, stream>>>(ei, bcur, bdata, E, NB);
    fine_hist<<<NB, 256, 0, stream>>>(bdata, bbase, dinv, N);

    int nbMM = (N + 63) / 64;

    // Layer 1
    mm1_kernel<<<nbMM, 256, 0, stream>>>(x, wsw1, dinv, bufA, N);
    agg_lds<<<NB, 256, 0, stream>>>(bufA, bdata, bbase, dinv, b1, bufB, sums, N);

    // Layer 2
    mm2_kernel<<<nbMM, 256, 0, stream>>>(bufB, wsw2, sums, gn_w, gn_b, gn_ms, ln_w, ln_b, dinv,
                                         bufA, N);
    agg_lds<<<NB, 256, 0, stream>>>(bufA, bdata, bbase, dinv, b2, bufB, sums + 128, N);
    gnlnmax_kernel<<<512, 256, 0, stream>>>(bufB, sums + 128, gn_w, gn_b, gn_ms, ln_w, ln_b,
                                            pooled, N);

    final_kernel<<<1, 64, 0, stream>>>(pooled, fc_W, fc_b, out);
}

// Round 8
// 340.064 us; speedup vs baseline: 4.3009x; 4.3009x over previous
//
#include <hip/hip_runtime.h>
#include <hip/hip_bf16.h>

#define EPSV 1e-5f
#define CHUNK 256   // dst nodes per bucket (bucket = dst >> 8)
#define MAXNB 512   // supports N <= 131072

typedef __attribute__((ext_vector_type(8))) short bf16x8;
typedef __attribute__((ext_vector_type(4))) float f32x4;

__device__ __forceinline__ ushort f2bf(float f) {
    union { float f; unsigned u; } c; c.f = f;
    unsigned u = c.u;
    return (ushort)((u + 0x7fffu + ((u >> 16) & 1u)) >> 16);
}
__device__ __forceinline__ float bf2f(ushort h) {
    union { unsigned u; float f; } c; c.u = ((unsigned)h) << 16;
    return c.f;
}
__device__ __forceinline__ float bflo(unsigned u) {
    union { unsigned u; float f; } c; c.u = u << 16;
    return c.f;
}
__device__ __forceinline__ float bfhi(unsigned u) {
    union { unsigned u; float f; } c; c.u = u & 0xFFFF0000u;
    return c.f;
}
// accumulate 8 bf16 features from a uint4 into a[0..7]
__device__ __forceinline__ void acc8(float* a, uint4 u) {
    a[0] += bflo(u.x); a[1] += bfhi(u.x);
    a[2] += bflo(u.y); a[3] += bfhi(u.y);
    a[4] += bflo(u.z); a[5] += bfhi(u.z);
    a[6] += bflo(u.w); a[7] += bfhi(u.w);
}

// ---------- bucketed CSR build ----------
// pack: low 20 bits = src (N < 2^20), bits 20..27 = dst & 255

__global__ void bucket_hist(const int* __restrict__ ei, int* __restrict__ bcnt, int E, int NB) {
    __shared__ int h[MAXNB];
    for (int b = threadIdx.x; b < NB; b += 256) h[b] = 0;
    __syncthreads();
    int stride = gridDim.x * 256;
    for (int e = blockIdx.x * 256 + threadIdx.x; e < E; e += stride)
        atomicAdd(&h[ei[E + e] >> 8], 1);
    __syncthreads();
    for (int b = threadIdx.x; b < NB; b += 256)
        if (h[b]) atomicAdd(&bcnt[b], h[b]);
}

// scan over buckets + W pre-swizzle (fused: both tiny, saves a dispatch)
__global__ void bucket_scan(const int* __restrict__ bcnt, int* __restrict__ bbase,
                            int* __restrict__ bcur, int* __restrict__ rp, int NB, int N,
                            const float* __restrict__ W1, const float* __restrict__ W2,
                            ushort* __restrict__ wsw1, ushort* __restrict__ wsw2) {
    __shared__ int sd[MAXNB];
    int t = threadIdx.x;
    int v = (t < NB) ? bcnt[t] : 0;
    sd[t] = v;
    __syncthreads();
    for (int off = 1; off < MAXNB; off <<= 1) {
        int x = (t >= off) ? sd[t - off] : 0;
        __syncthreads();
        sd[t] += x;
        __syncthreads();
    }
    int excl = sd[t] - v;
    if (t < NB) { bbase[t] = excl; bcur[t] = excl; }
    if (t == MAXNB - 1) {
        bbase[NB] = sd[MAXNB - 1];
        rp[N] = sd[MAXNB - 1];  // == E
    }
    // W pre-swizzle into MFMA B-fragment order: (k,n) -> [((k>>3)*64+n)*8+(k&7)]
    for (int i = t; i < 128 * 64; i += MAXNB) {
        int k = i >> 6, n = i & 63;
        wsw1[((k >> 3) * 64 + n) * 8 + (k & 7)] = f2bf(W1[i]);
    }
    for (int i = t; i < 64 * 64; i += MAXNB) {
        int k = i >> 6, n = i & 63;
        wsw2[((k >> 3) * 64 + n) * 8 + (k & 7)] = f2bf(W2[i]);
    }
}

#define EPB 8192  // edges per bucket_scatter block

__global__ void __launch_bounds__(256) bucket_scatter(const int* __restrict__ ei,
                                                      int* __restrict__ bcur,
                                                      unsigned* __restrict__ bdata, int E,
                                                      int NB) {
    __shared__ int h[MAXNB];
    __shared__ int cur[MAXNB];
    int base = blockIdx.x * EPB;
    int end = min(base + EPB, E);
    for (int b = threadIdx.x; b < NB; b += 256) h[b] = 0;
    __syncthreads();
    for (int e = base + threadIdx.x; e < end; e += 256)
        atomicAdd(&h[ei[E + e] >> 8], 1);
    __syncthreads();
    for (int b = threadIdx.x; b < NB; b += 256) {
        int c = h[b];
        cur[b] = c ? atomicAdd(&bcur[b], c) : 0;
    }
    __syncthreads();
    for (int e = base + threadIdx.x; e < end; e += 256) {
        int s = ei[e], d = ei[E + e];
        int pos = atomicAdd(&cur[d >> 8], 1);
        bdata[pos] = (unsigned)s | ((unsigned)(d & (CHUNK - 1)) << 20);
    }
}

// fused: per-bucket hist -> local scan -> rp/dinv -> scatter (srcs pre-shifted: src*8)
__global__ void __launch_bounds__(256) bucket_finish(const unsigned* __restrict__ bdata,
                                                     const int* __restrict__ bbase,
                                                     int* __restrict__ rp,
                                                     float* __restrict__ dinv,
                                                     int* __restrict__ srcs, int N) {
    __shared__ int h[CHUNK];
    __shared__ int cur[CHUNK];
    int t = threadIdx.x;
    h[t] = 0;
    __syncthreads();
    int beg = bbase[blockIdx.x], end = bbase[blockIdx.x + 1];
    for (int e = beg + t; e < end; e += 256) atomicAdd(&h[bdata[e] >> 20], 1);
    __syncthreads();
    int v = h[t];
    cur[t] = v;
    __syncthreads();
    for (int off = 1; off < 256; off <<= 1) {
        int x = (t >= off) ? cur[t - off] : 0;
        __syncthreads();
        cur[t] += x;
        __syncthreads();
    }
    int r = beg + cur[t] - v;  // exclusive prefix within bucket
    int node = blockIdx.x * CHUNK + t;
    if (node < N) {
        rp[node] = r;
        dinv[node] = rsqrtf((float)v + 1.0f);
    }
    cur[t] = r;
    __syncthreads();
    for (int e = beg + t; e < end; e += 256) {
        unsigned p = bdata[e];
        int pos = atomicAdd(&cur[p >> 20], 1);
        srcs[pos] = (int)((p & 0xFFFFFu) << 3);  // src * 8 (uint4 row offset)
    }
}

// ---------- matmul1: Ht[N,64](bf16) = dinv[r] * (X[N,128](fp32) @ W1) ----------

__global__ void __launch_bounds__(256) mm1_kernel(const float* __restrict__ X,
                                                  const ushort* __restrict__ wsw,
                                                  const float* __restrict__ dinv,
                                                  ushort* __restrict__ Ht, int N) {
    const int KO = 4;
    int w = threadIdx.x >> 6, lane = threadIdx.x & 63;
    int m = lane & 15, q = lane >> 4;
    int row = blockIdx.x * 64 + w * 16 + m;

    bf16x8 afrag[KO];
#pragma unroll
    for (int kk = 0; kk < KO; kk++) {
        float xv[8];
        if (row < N) {
            const float4* xp = reinterpret_cast<const float4*>(X + (size_t)row * 128 + kk * 32 + q * 8);
            float4 v0 = xp[0], v1 = xp[1];
            xv[0] = v0.x; xv[1] = v0.y; xv[2] = v0.z; xv[3] = v0.w;
            xv[4] = v1.x; xv[5] = v1.y; xv[6] = v1.z; xv[7] = v1.w;
        } else {
#pragma unroll
            for (int j = 0; j < 8; j++) xv[j] = 0.f;
        }
#pragma unroll
        for (int j = 0; j < 8; j++) afrag[kk][j] = (short)f2bf(xv[j]);
    }

    float dv[4];
#pragma unroll
    for (int reg = 0; reg < 4; reg++) {
        int r = blockIdx.x * 64 + w * 16 + q * 4 + reg;
        dv[reg] = (r < N) ? dinv[r] : 0.f;
    }

    const bf16x8* wp = reinterpret_cast<const bf16x8*>(wsw);
#pragma unroll
    for (int ct = 0; ct < 4; ct++) {
        f32x4 acc = {0.f, 0.f, 0.f, 0.f};
#pragma unroll
        for (int kk = 0; kk < KO; kk++) {
            bf16x8 b = wp[(kk * 4 + q) * 64 + ct * 16 + m];
            acc = __builtin_amdgcn_mfma_f32_16x16x32_bf16(afrag[kk], b, acc, 0, 0, 0);
        }
#pragma unroll
        for (int reg = 0; reg < 4; reg++) {
            int r = blockIdx.x * 64 + w * 16 + q * 4 + reg;
            if (r < N) Ht[(size_t)r * 64 + ct * 16 + m] = f2bf(acc[reg] * dv[reg]);
        }
    }
}

// ---------- matmul2: fused GraphNorm+LayerNorm on A, then Ht2 = dinv * (norm(A) @ W2) ----------

__global__ void __launch_bounds__(256) mm2_kernel(
    const ushort* __restrict__ A2, const ushort* __restrict__ wsw,
    const float* __restrict__ sums, const float* __restrict__ gn_w,
    const float* __restrict__ gn_b, const float* __restrict__ gn_ms,
    const float* __restrict__ ln_w, const float* __restrict__ ln_b,
    const float* __restrict__ dinv, ushort* __restrict__ Ht, int N) {
    __shared__ float sg[64], tg[64], lwv[64], lbv[64];
    int t = threadIdx.x;
    if (t < 64) {
        float invN = 1.0f / (float)N;
        float mean = sums[t] * invN;
        float m2 = sums[64 + t] * invN;
        float ms = gn_ms[t];
        float var = m2 - 2.f * ms * mean * mean + ms * ms * mean * mean;
        float s = gn_w[t] * rsqrtf(var + EPSV);
        sg[t] = s;
        tg[t] = gn_b[t] - s * ms * mean;
        lwv[t] = ln_w[t];
        lbv[t] = ln_b[t];
    }
    __syncthreads();

    int w = t >> 6, lane = t & 63;
    int m = lane & 15, q = lane >> 4;
    int row = blockIdx.x * 64 + w * 16 + m;

    float g[16];
#pragma unroll
    for (int kk = 0; kk < 2; kk++) {
        uint4 u = make_uint4(0, 0, 0, 0);
        if (row < N)
            u = *reinterpret_cast<const uint4*>(A2 + (size_t)row * 64 + kk * 32 + q * 8);
        unsigned uu[4] = {u.x, u.y, u.z, u.w};
#pragma unroll
        for (int p = 0; p < 4; p++) {
            int f0 = kk * 32 + q * 8 + 2 * p;
            g[kk * 8 + 2 * p] = sg[f0] * bflo(uu[p]) + tg[f0];
            g[kk * 8 + 2 * p + 1] = sg[f0 + 1] * bfhi(uu[p]) + tg[f0 + 1];
        }
    }
    float s1 = 0.f;
#pragma unroll
    for (int i = 0; i < 16; i++) s1 += g[i];
    s1 += __shfl_xor(s1, 16);
    s1 += __shfl_xor(s1, 32);
    float mu = s1 * (1.f / 64.f);
    float s2 = 0.f;
#pragma unroll
    for (int i = 0; i < 16; i++) {
        float c = g[i] - mu;
        s2 += c * c;
    }
    s2 += __shfl_xor(s2, 16);
    s2 += __shfl_xor(s2, 32);
    float rs = rsqrtf(s2 * (1.f / 64.f) + EPSV);

    bf16x8 afrag[2];
#pragma unroll
    for (int kk = 0; kk < 2; kk++) {
#pragma unroll
        for (int j = 0; j < 8; j++) {
            int f = kk * 32 + q * 8 + j;
            float y = lwv[f] * (g[kk * 8 + j] - mu) * rs + lbv[f];
            afrag[kk][j] = (short)f2bf(y);
        }
    }

    float dv[4];
#pragma unroll
    for (int reg = 0; reg < 4; reg++) {
        int r = blockIdx.x * 64 + w * 16 + q * 4 + reg;
        dv[reg] = (r < N) ? dinv[r] : 0.f;
    }

    const bf16x8* wp = reinterpret_cast<const bf16x8*>(wsw);
#pragma unroll
    for (int ct = 0; ct < 4; ct++) {
        f32x4 acc = {0.f, 0.f, 0.f, 0.f};
#pragma unroll
        for (int kk = 0; kk < 2; kk++) {
            bf16x8 b = wp[(kk * 4 + q) * 64 + ct * 16 + m];
            acc = __builtin_amdgcn_mfma_f32_16x16x32_bf16(afrag[kk], b, acc, 0, 0, 0);
        }
#pragma unroll
        for (int reg = 0; reg < 4; reg++) {
            int r = blockIdx.x * 64 + w * 16 + q * 4 + reg;
            if (r < N) Ht[(size_t)r * 64 + ct * 16 + m] = f2bf(acc[reg] * dv[reg]);
        }
    }
}

// ---------- edge aggregation v6: group-per-node, 8 rows per VMEM instr ----------
// wave = 8 groups x 8 lanes; group g owns node jo*8+g, walks its srcs sequentially.
// Row = 8 lanes x uint4 (128B). Unroll 4 -> 32 rows in flight per wave. No shfl,
// no cross-group reduction in the hot loop. srcs holds src*8 (uint4 row offset);
// tail slots clamp to zero row at Ht[N] (ZR = N*8).

__global__ void __launch_bounds__(256) agg_kernel(
    const ushort* __restrict__ Ht, const int* __restrict__ rp, const int* __restrict__ srcs,
    const float* __restrict__ dinv, const float* __restrict__ bias,
    ushort* __restrict__ out, float* __restrict__ sums, int N) {
    int t = threadIdx.x;
    int lane = t & 63;
    int g = lane >> 3, fq = lane & 7;
    int wid = (blockIdx.x * blockDim.x + t) >> 6;
    int nw = (gridDim.x * blockDim.x) >> 6;
    const uint4* H4 = reinterpret_cast<const uint4*>(Ht);
    uint4* O4 = reinterpret_cast<uint4*>(out);
    const int ZR = N * 8;
    float bb[8];
#pragma unroll
    for (int j = 0; j < 8; j++) bb[j] = bias[fq * 8 + j];
    float ps1[8] = {0, 0, 0, 0, 0, 0, 0, 0}, ps2[8] = {0, 0, 0, 0, 0, 0, 0, 0};

    for (int jo = wid; jo * 8 < N; jo += nw) {
        int node = jo * 8 + g;
        bool valid = node < N;
        int beg = 0, end = 0;
        float di = 0.f;
        if (valid) {
            beg = rp[node];
            end = rp[node + 1];
            di = dinv[node];
        }
        float a[8] = {0, 0, 0, 0, 0, 0, 0, 0};
        for (int e = beg; e < end; e += 4) {
            int last = end - 1;
            int e1 = e + 1 < last ? e + 1 : last;
            int e2 = e + 2 < last ? e + 2 : last;
            int e3 = e + 3 < last ? e + 3 : last;
            int s0 = srcs[e];
            int s1 = srcs[e1];
            int s2 = srcs[e2];
            int s3 = srcs[e3];
            s1 = (e + 1 <= last) ? s1 : ZR;
            s2 = (e + 2 <= last) ? s2 : ZR;
            s3 = (e + 3 <= last) ? s3 : ZR;
            uint4 u0 = H4[s0 + fq];
            uint4 u1 = H4[s1 + fq];
            uint4 u2 = H4[s2 + fq];
            uint4 u3 = H4[s3 + fq];
            acc8(a, u0);
            acc8(a, u1);
            acc8(a, u2);
            acc8(a, u3);
        }
        uint4 us = H4[(valid ? node * 8 : ZR) + fq];
        float sf[8] = {bflo(us.x), bfhi(us.x), bflo(us.y), bfhi(us.y),
                       bflo(us.z), bfhi(us.z), bflo(us.w), bfhi(us.w)};
        float vv[8];
#pragma unroll
        for (int j = 0; j < 8; j++) vv[j] = fmaxf(di * a[j] + di * sf[j] + bb[j], 0.f);
        if (valid) {
            uint4 o;
            o.x = (unsigned)f2bf(vv[0]) | ((unsigned)f2bf(vv[1]) << 16);
            o.y = (unsigned)f2bf(vv[2]) | ((unsigned)f2bf(vv[3]) << 16);
            o.z = (unsigned)f2bf(vv[4]) | ((unsigned)f2bf(vv[5]) << 16);
            o.w = (unsigned)f2bf(vv[6]) | ((unsigned)f2bf(vv[7]) << 16);
            O4[(size_t)node * 8 + fq] = o;
#pragma unroll
            for (int j = 0; j < 8; j++) {
                ps1[j] += vv[j];
                ps2[j] += vv[j] * vv[j];
            }
        }
    }

    // colstats: reduce across the 8 groups (same fq -> same features), stage in LDS
    __shared__ float red[4][128];
    int wv = t >> 6;
#pragma unroll
    for (int j = 0; j < 8; j++) {
        float s = ps1[j], q = ps2[j];
        s += __shfl_xor(s, 8); s += __shfl_xor(s, 16); s += __shfl_xor(s, 32);
        q += __shfl_xor(q, 8); q += __shfl_xor(q, 16); q += __shfl_xor(q, 32);
        if (g == 0) {
            red[wv][fq * 8 + j] = s;
            red[wv][64 + fq * 8 + j] = q;
        }
    }
    __syncthreads();
    if (t < 128) {
        float v = red[0][t] + red[1][t] + red[2][t] + red[3][t];
        atomicAdd(&sums[t], v);
    }
}

// ---------- layer-2 norms + max-pool ----------

__device__ __forceinline__ float gn_ln_row(float x, float mean, float var, float ms, float gw,
                                           float gb, float lw, float lb) {
    float g = gw * (x - ms * mean) * rsqrtf(var + EPSV) + gb;
    float mu = g;
#pragma unroll
    for (int off = 32; off; off >>= 1) mu += __shfl_xor(mu, off);
    mu *= (1.f / 64.f);
    float c = g - mu;
    float vv = c * c;
#pragma unroll
    for (int off = 32; off; off >>= 1) vv += __shfl_xor(vv, off);
    vv *= (1.f / 64.f);
    return lw * c * rsqrtf(vv + EPSV) + lb;
}

__device__ __forceinline__ unsigned fkey(float f) {
    unsigned u = __float_as_uint(f);
    return (u & 0x80000000u) ? ~u : (u | 0x80000000u);
}

__global__ void gnlnmax_kernel(const ushort* __restrict__ A, const float* __restrict__ sums,
                               const float* __restrict__ gn_w, const float* __restrict__ gn_b,
                               const float* __restrict__ gn_ms, const float* __restrict__ ln_w,
                               const float* __restrict__ ln_b, unsigned* __restrict__ pooled,
                               int N) {
    __shared__ float lmax[256];
    int lane = threadIdx.x & 63;
    int wave0 = (blockIdx.x * blockDim.x + threadIdx.x) >> 6;
    int nw = (gridDim.x * blockDim.x) >> 6;
    float invN = 1.0f / (float)N;
    float mean = sums[lane] * invN;
    float m2 = sums[64 + lane] * invN;
    float ms = gn_ms[lane];
    float var = m2 - 2.f * ms * mean * mean + ms * ms * mean * mean;
    float gw = gn_w[lane], gb = gn_b[lane], lw = ln_w[lane], lb = ln_b[lane];
    float mx = -3.4e38f;
    for (int i = wave0; i < N; i += nw) {
        float y = gn_ln_row(bf2f(A[(size_t)i * 64 + lane]), mean, var, ms, gw, gb, lw, lb);
        mx = fmaxf(mx, y);
    }
    lmax[threadIdx.x] = mx;
    __syncthreads();
    if (threadIdx.x < 64) {
        float m = fmaxf(fmaxf(lmax[threadIdx.x], lmax[threadIdx.x + 64]),
                        fmaxf(lmax[threadIdx.x + 128], lmax[threadIdx.x + 192]));
        atomicMax(&pooled[threadIdx.x], fkey(m));
    }
}

// ---------- final FC ----------

__global__ void final_kernel(const unsigned* __restrict__ pooled, const float* __restrict__ fc_W,
                             const float* __restrict__ fc_b, float* __restrict__ out) {
    __shared__ float p[64];
    int t = threadIdx.x;
    if (t < 64) {
        unsigned u = pooled[t];
        p[t] = (u & 0x80000000u) ? __uint_as_float(u ^ 0x80000000u) : __uint_as_float(~u);
    }
    __syncthreads();
    if (t < 32) {
        float acc = fc_b[t];
#pragma unroll
        for (int f = 0; f < 64; f++) acc += p[f] * fc_W[f * 32 + t];
        out[t] = acc;
    }
}

// ---------- launch ----------

static inline size_t align_up(size_t v, size_t a) { return (v + a - 1) & ~(a - 1); }

extern "C" void kernel_launch(void* const* d_in, const int* in_sizes, int n_in, void* d_out,
                              int out_size, void* d_ws, size_t ws_size, hipStream_t stream) {
    const float* x = (const float*)d_in[0];
    const int* ei = (const int*)d_in[1];
    const float* W1 = (const float*)d_in[2];
    const float* b1 = (const float*)d_in[3];
    const float* W2 = (const float*)d_in[4];
    const float* b2 = (const float*)d_in[5];
    const float* gn_w = (const float*)d_in[6];
    const float* gn_b = (const float*)d_in[7];
    const float* gn_ms = (const float*)d_in[8];
    const float* ln_w = (const float*)d_in[9];
    const float* ln_b = (const float*)d_in[10];
    const float* fc_W = (const float*)d_in[11];
    const float* fc_b = (const float*)d_in[12];
    float* out = (float*)d_out;

    const int N = in_sizes[0] / 128;
    const int E = in_sizes[1] / 2;
    const int NB = (N + CHUNK - 1) / CHUNK;

    char* ws = (char*)d_ws;
    size_t off = 0;
    auto alloc = [&](size_t bytes) {
        char* p = ws + off;
        off = align_up(off + bytes, 256);
        return p;
    };
    int* rp = (int*)alloc((size_t)(N + 1) * 4);
    int* bbase = (int*)alloc((size_t)(NB + 1) * 4);
    int* bcur = (int*)alloc((size_t)(NB + 1) * 4);
    float* dinv = (float*)alloc((size_t)N * 4);
    unsigned* bdata = (unsigned*)alloc((size_t)E * 4);
    int* srcs = (int*)alloc((size_t)(E + 16) * 4);
    ushort* bufB = (ushort*)alloc((size_t)N * 64 * 2);
    ushort* wsw1 = (ushort*)alloc(128 * 64 * 2);
    ushort* wsw2 = (ushort*)alloc(64 * 64 * 2);
    ushort* bufA = (ushort*)alloc((size_t)N * 64 * 2);  // gather source; zero row follows
    // ---- single contiguous zero-init region: [zrow][bcnt][sums][pooled] ----
    size_t zoff = off;
    ushort* zrow = (ushort*)alloc(128);  // bufA row N (contiguous with bufA)
    int* bcnt = (int*)alloc((size_t)(NB + 1) * 4);
    float* sums = (float*)alloc(256 * 4);
    unsigned* pooled = (unsigned*)alloc(64 * 4);
    size_t zlen = off - zoff;
    (void)zrow;

    hipMemsetAsync(ws + zoff, 0, zlen, stream);

    // CSR build (bucketed)
    int nbB = (E + EPB - 1) / EPB;
    bucket_hist<<<256, 256, 0, stream>>>(ei, bcnt, E, NB);
    bucket_scan<<<1, MAXNB, 0, stream>>>(bcnt, bbase, bcur, rp, NB, N, W1, W2, wsw1, wsw2);
    bucket_scatter<<<nbB, 256, 0, stream>>>(ei, bcur, bdata, E, NB);
    bucket_finish<<<NB, 256, 0, stream>>>(bdata, bbase, rp, dinv, srcs, N);

    int nbMM = (N + 63) / 64;
    int nbAgg = 782;  // ~4 node-octets per wave (balanced grid-stride)

    // Layer 1
    mm1_kernel<<<nbMM, 256, 0, stream>>>(x, wsw1, dinv, bufA, N);
    agg_kernel<<<nbAgg, 256, 0, stream>>>(bufA, rp, srcs, dinv, b1, bufB, sums, N);

    // Layer 2
    mm2_kernel<<<nbMM, 256, 0, stream>>>(bufB, wsw2, sums, gn_w, gn_b, gn_ms, ln_w, ln_b, dinv,
                                         bufA, N);
    agg_kernel<<<nbAgg, 256, 0, stream>>>(bufA, rp, srcs, dinv, b2, bufB, sums + 128, N);
    gnlnmax_kernel<<<512, 256, 0, stream>>>(bufB, sums + 128, gn_w, gn_b, gn_ms, ln_w, ln_b,
                                            pooled, N);

    final_kernel<<<1, 64, 0, stream>>>(pooled, fc_W, fc_b, out);
}

// Round 9
// 305.267 us; speedup vs baseline: 4.7912x; 1.1140x over previous
//
#include <hip/hip_runtime.h>
#include <hip/hip_bf16.h>

#define EPSV 1e-5f
#define CHUNK 256   // dst nodes per bucket (bucket = dst >> 8)
#define CAP 6144    // slots per bucket (mean 4096, +16 sigma + padding)
#define MAXNB 512   // supports N <= 131072

typedef __attribute__((ext_vector_type(8))) short bf16x8;
typedef __attribute__((ext_vector_type(4))) float f32x4;

__device__ __forceinline__ ushort f2bf(float f) {
    union { float f; unsigned u; } c; c.f = f;
    unsigned u = c.u;
    return (ushort)((u + 0x7fffu + ((u >> 16) & 1u)) >> 16);
}
__device__ __forceinline__ float bf2f(ushort h) {
    union { unsigned u; float f; } c; c.u = ((unsigned)h) << 16;
    return c.f;
}
__device__ __forceinline__ float bflo(unsigned u) {
    union { unsigned u; float f; } c; c.u = u << 16;
    return c.f;
}
__device__ __forceinline__ float bfhi(unsigned u) {
    union { unsigned u; float f; } c; c.u = u & 0xFFFF0000u;
    return c.f;
}
__device__ __forceinline__ void acc8(float* a, uint4 u) {
    a[0] += bflo(u.x); a[1] += bfhi(u.x);
    a[2] += bflo(u.y); a[3] += bfhi(u.y);
    a[4] += bflo(u.z); a[5] += bfhi(u.z);
    a[6] += bflo(u.w); a[7] += bfhi(u.w);
}

// ---------- prep: W swizzle + bucket cursor init (fixed-capacity buckets) ----------
// W (k,n) -> wsw[((k>>3)*64 + n)*8 + (k&7)]

__global__ void prep_kernel(const float* __restrict__ W1, const float* __restrict__ W2,
                            ushort* __restrict__ wsw1, ushort* __restrict__ wsw2,
                            int* __restrict__ bcur, int NB) {
    int t = blockIdx.x * blockDim.x + threadIdx.x;  // 48*256 = 12288
    if (t < 128 * 64) {
        int k = t >> 6, n = t & 63;
        wsw1[((k >> 3) * 64 + n) * 8 + (k & 7)] = f2bf(W1[t]);
    }
    if (t < 64 * 64) {
        int k = t >> 6, n = t & 63;
        wsw2[((k >> 3) * 64 + n) * 8 + (k & 7)] = f2bf(W2[t]);
    }
    if (t < NB) bcur[t] = t * CAP;
}

// ---------- bucket scatter: pack (src | dloc<<20) into fixed-cap bucket regions ----------

#define EPB 8192  // edges per block

__global__ void __launch_bounds__(256) bucket_scatter(const int* __restrict__ ei,
                                                      int* __restrict__ bcur,
                                                      unsigned* __restrict__ bdata, int E,
                                                      int NB) {
    __shared__ int h[MAXNB];
    __shared__ int cur[MAXNB];
    int t = threadIdx.x;
    int base = blockIdx.x * EPB;
    int end = min(base + EPB, E);
    for (int b = t; b < NB; b += 256) h[b] = 0;
    __syncthreads();
    // hist pass (int4 over dst; E and EPB divisible by 4)
    for (int e = base + t * 4; e < end; e += 1024) {
        int4 d4 = *reinterpret_cast<const int4*>(&ei[E + e]);
        atomicAdd(&h[d4.x >> 8], 1);
        atomicAdd(&h[d4.y >> 8], 1);
        atomicAdd(&h[d4.z >> 8], 1);
        atomicAdd(&h[d4.w >> 8], 1);
    }
    __syncthreads();
    for (int b = t; b < NB; b += 256) {
        int c = h[b];
        cur[b] = c ? atomicAdd(&bcur[b], c) : 0;
    }
    __syncthreads();
    for (int e = base + t * 4; e < end; e += 1024) {
        int4 s4 = *reinterpret_cast<const int4*>(&ei[e]);
        int4 d4 = *reinterpret_cast<const int4*>(&ei[E + e]);
        int p0 = atomicAdd(&cur[d4.x >> 8], 1);
        bdata[p0] = (unsigned)s4.x | ((unsigned)(d4.x & 255) << 20);
        int p1 = atomicAdd(&cur[d4.y >> 8], 1);
        bdata[p1] = (unsigned)s4.y | ((unsigned)(d4.y & 255) << 20);
        int p2 = atomicAdd(&cur[d4.z >> 8], 1);
        bdata[p2] = (unsigned)s4.z | ((unsigned)(d4.z & 255) << 20);
        int p3 = atomicAdd(&cur[d4.w >> 8], 1);
        bdata[p3] = (unsigned)s4.w | ((unsigned)(d4.w & 255) << 20);
    }
}

// ---------- bucket finish: per-bucket hist -> padded scan -> nodeinfo/dinv -> scatter ----------
// srcs lists padded to multiple of 4 with ZR (= N*8) entries; srcs holds src*8.

__global__ void __launch_bounds__(256) bucket_finish(const unsigned* __restrict__ bdata,
                                                     const int* __restrict__ bcur,
                                                     int2* __restrict__ NI,
                                                     float* __restrict__ dinv,
                                                     int* __restrict__ srcs, int N) {
    __shared__ int h[CHUNK];
    __shared__ int cur[CHUNK];
    int t = threadIdx.x;
    int beg = blockIdx.x * CAP;
    int end = bcur[blockIdx.x];
    h[t] = 0;
    __syncthreads();
    for (int e = beg + t; e < end; e += 256) atomicAdd(&h[bdata[e] >> 20], 1);
    __syncthreads();
    int deg = h[t];
    int pc = (deg + 3) & ~3;
    cur[t] = pc;
    __syncthreads();
    for (int off = 1; off < 256; off <<= 1) {
        int x = (t >= off) ? cur[t - off] : 0;
        __syncthreads();
        cur[t] += x;
        __syncthreads();
    }
    int begp = beg + cur[t] - pc;  // padded start for this node's list
    int node = blockIdx.x * CHUNK + t;
    if (node < N) {
        NI[node] = make_int2(begp, pc);
        dinv[node] = rsqrtf((float)deg + 1.0f);
    }
    h[t] = begp;
    __syncthreads();
    for (int e = beg + t; e < end; e += 256) {
        unsigned p = bdata[e];
        int pos = atomicAdd(&h[p >> 20], 1);
        srcs[pos] = (int)((p & 0xFFFFFu) << 3);  // src * 8 (uint4 row offset)
    }
    __syncthreads();
    // pad fill: h[t] is now begp+deg
    int zr = N * 8;
    for (int k = h[t]; k < begp + pc; k++) srcs[k] = zr;
}

// ---------- matmul1: Ht[N,64](bf16) = dinv[r] * (X[N,128](fp32) @ W1) ----------

__global__ void __launch_bounds__(256) mm1_kernel(const float* __restrict__ X,
                                                  const ushort* __restrict__ wsw,
                                                  const float* __restrict__ dinv,
                                                  ushort* __restrict__ Ht, int N) {
    const int KO = 4;
    int w = threadIdx.x >> 6, lane = threadIdx.x & 63;
    int m = lane & 15, q = lane >> 4;
    int row = blockIdx.x * 64 + w * 16 + m;

    bf16x8 afrag[KO];
#pragma unroll
    for (int kk = 0; kk < KO; kk++) {
        float xv[8];
        if (row < N) {
            const float4* xp = reinterpret_cast<const float4*>(X + (size_t)row * 128 + kk * 32 + q * 8);
            float4 v0 = xp[0], v1 = xp[1];
            xv[0] = v0.x; xv[1] = v0.y; xv[2] = v0.z; xv[3] = v0.w;
            xv[4] = v1.x; xv[5] = v1.y; xv[6] = v1.z; xv[7] = v1.w;
        } else {
#pragma unroll
            for (int j = 0; j < 8; j++) xv[j] = 0.f;
        }
#pragma unroll
        for (int j = 0; j < 8; j++) afrag[kk][j] = (short)f2bf(xv[j]);
    }

    float dv[4];
#pragma unroll
    for (int reg = 0; reg < 4; reg++) {
        int r = blockIdx.x * 64 + w * 16 + q * 4 + reg;
        dv[reg] = (r < N) ? dinv[r] : 0.f;
    }

    const bf16x8* wp = reinterpret_cast<const bf16x8*>(wsw);
#pragma unroll
    for (int ct = 0; ct < 4; ct++) {
        f32x4 acc = {0.f, 0.f, 0.f, 0.f};
#pragma unroll
        for (int kk = 0; kk < KO; kk++) {
            bf16x8 b = wp[(kk * 4 + q) * 64 + ct * 16 + m];
            acc = __builtin_amdgcn_mfma_f32_16x16x32_bf16(afrag[kk], b, acc, 0, 0, 0);
        }
#pragma unroll
        for (int reg = 0; reg < 4; reg++) {
            int r = blockIdx.x * 64 + w * 16 + q * 4 + reg;
            if (r < N) Ht[(size_t)r * 64 + ct * 16 + m] = f2bf(acc[reg] * dv[reg]);
        }
    }
}

// ---------- matmul2: fused GraphNorm+LayerNorm on A, then Ht2 = dinv * (norm(A) @ W2) ----------

__global__ void __launch_bounds__(256) mm2_kernel(
    const ushort* __restrict__ A2, const ushort* __restrict__ wsw,
    const float* __restrict__ sums, const float* __restrict__ gn_w,
    const float* __restrict__ gn_b, const float* __restrict__ gn_ms,
    const float* __restrict__ ln_w, const float* __restrict__ ln_b,
    const float* __restrict__ dinv, ushort* __restrict__ Ht, int N) {
    __shared__ float sg[64], tg[64], lwv[64], lbv[64];
    int t = threadIdx.x;
    if (t < 64) {
        float invN = 1.0f / (float)N;
        float mean = sums[t] * invN;
        float m2 = sums[64 + t] * invN;
        float ms = gn_ms[t];
        float var = m2 - 2.f * ms * mean * mean + ms * ms * mean * mean;
        float s = gn_w[t] * rsqrtf(var + EPSV);
        sg[t] = s;
        tg[t] = gn_b[t] - s * ms * mean;
        lwv[t] = ln_w[t];
        lbv[t] = ln_b[t];
    }
    __syncthreads();

    int w = t >> 6, lane = t & 63;
    int m = lane & 15, q = lane >> 4;
    int row = blockIdx.x * 64 + w * 16 + m;

    float g[16];
#pragma unroll
    for (int kk = 0; kk < 2; kk++) {
        uint4 u = make_uint4(0, 0, 0, 0);
        if (row < N)
            u = *reinterpret_cast<const uint4*>(A2 + (size_t)row * 64 + kk * 32 + q * 8);
        unsigned uu[4] = {u.x, u.y, u.z, u.w};
#pragma unroll
        for (int p = 0; p < 4; p++) {
            int f0 = kk * 32 + q * 8 + 2 * p;
            g[kk * 8 + 2 * p] = sg[f0] * bflo(uu[p]) + tg[f0];
            g[kk * 8 + 2 * p + 1] = sg[f0 + 1] * bfhi(uu[p]) + tg[f0 + 1];
        }
    }
    float s1 = 0.f;
#pragma unroll
    for (int i = 0; i < 16; i++) s1 += g[i];
    s1 += __shfl_xor(s1, 16);
    s1 += __shfl_xor(s1, 32);
    float mu = s1 * (1.f / 64.f);
    float s2 = 0.f;
#pragma unroll
    for (int i = 0; i < 16; i++) {
        float c = g[i] - mu;
        s2 += c * c;
    }
    s2 += __shfl_xor(s2, 16);
    s2 += __shfl_xor(s2, 32);
    float rs = rsqrtf(s2 * (1.f / 64.f) + EPSV);

    bf16x8 afrag[2];
#pragma unroll
    for (int kk = 0; kk < 2; kk++) {
#pragma unroll
        for (int j = 0; j < 8; j++) {
            int f = kk * 32 + q * 8 + j;
            float y = lwv[f] * (g[kk * 8 + j] - mu) * rs + lbv[f];
            afrag[kk][j] = (short)f2bf(y);
        }
    }

    float dv[4];
#pragma unroll
    for (int reg = 0; reg < 4; reg++) {
        int r = blockIdx.x * 64 + w * 16 + q * 4 + reg;
        dv[reg] = (r < N) ? dinv[r] : 0.f;
    }

    const bf16x8* wp = reinterpret_cast<const bf16x8*>(wsw);
#pragma unroll
    for (int ct = 0; ct < 4; ct++) {
        f32x4 acc = {0.f, 0.f, 0.f, 0.f};
#pragma unroll
        for (int kk = 0; kk < 2; kk++) {
            bf16x8 b = wp[(kk * 4 + q) * 64 + ct * 16 + m];
            acc = __builtin_amdgcn_mfma_f32_16x16x32_bf16(afrag[kk], b, acc, 0, 0, 0);
        }
#pragma unroll
        for (int reg = 0; reg < 4; reg++) {
            int r = blockIdx.x * 64 + w * 16 + q * 4 + reg;
            if (r < N) Ht[(size_t)r * 64 + ct * 16 + m] = f2bf(acc[reg] * dv[reg]);
        }
    }
}

// ---------- edge aggregation v7: group-per-node, padded lists, int4 indices, unroll 8 ----------
// wave = 8 groups x 8 lanes; group g owns node jo*8+g. Lists are padded to x4 with
// zero-row entries (no clamps). 2 x dwordx4 index loads + 8 row gathers in flight.

__global__ void __launch_bounds__(256) agg_kernel(
    const ushort* __restrict__ Ht, const int2* __restrict__ NI, const int* __restrict__ srcs,
    const float* __restrict__ dinv, const float* __restrict__ bias,
    ushort* __restrict__ out, float* __restrict__ sums, int N) {
    int t = threadIdx.x;
    int lane = t & 63;
    int g = lane >> 3, fq = lane & 7;
    int wid = (blockIdx.x * blockDim.x + t) >> 6;
    int nw = (gridDim.x * blockDim.x) >> 6;
    const uint4* H4 = reinterpret_cast<const uint4*>(Ht);
    uint4* O4 = reinterpret_cast<uint4*>(out);
    const int ZR = N * 8;
    float bb[8];
#pragma unroll
    for (int j = 0; j < 8; j++) bb[j] = bias[fq * 8 + j];
    float ps1[8] = {0, 0, 0, 0, 0, 0, 0, 0}, ps2[8] = {0, 0, 0, 0, 0, 0, 0, 0};

    for (int jo = wid; jo * 8 < N; jo += nw) {
        int node = jo * 8 + g;
        bool valid = node < N;
        int2 info = valid ? NI[node] : make_int2(0, 0);
        float di = valid ? dinv[node] : 0.f;
        int e = info.x, end = info.x + info.y;
        float a[8] = {0, 0, 0, 0, 0, 0, 0, 0};
        for (; e + 8 <= end; e += 8) {
            int4 i0 = *reinterpret_cast<const int4*>(&srcs[e]);
            int4 i1 = *reinterpret_cast<const int4*>(&srcs[e + 4]);
            uint4 u0 = H4[i0.x + fq];
            uint4 u1 = H4[i0.y + fq];
            uint4 u2 = H4[i0.z + fq];
            uint4 u3 = H4[i0.w + fq];
            uint4 u4 = H4[i1.x + fq];
            uint4 u5 = H4[i1.y + fq];
            uint4 u6 = H4[i1.z + fq];
            uint4 u7 = H4[i1.w + fq];
            acc8(a, u0); acc8(a, u1); acc8(a, u2); acc8(a, u3);
            acc8(a, u4); acc8(a, u5); acc8(a, u6); acc8(a, u7);
        }
        if (e < end) {  // remainder is exactly 4 (lists padded to x4)
            int4 i0 = *reinterpret_cast<const int4*>(&srcs[e]);
            uint4 u0 = H4[i0.x + fq];
            uint4 u1 = H4[i0.y + fq];
            uint4 u2 = H4[i0.z + fq];
            uint4 u3 = H4[i0.w + fq];
            acc8(a, u0); acc8(a, u1); acc8(a, u2); acc8(a, u3);
        }
        uint4 us = H4[(valid ? node * 8 : ZR) + fq];
        float sf[8] = {bflo(us.x), bfhi(us.x), bflo(us.y), bfhi(us.y),
                       bflo(us.z), bfhi(us.z), bflo(us.w), bfhi(us.w)};
        float vv[8];
#pragma unroll
        for (int j = 0; j < 8; j++) vv[j] = fmaxf(di * a[j] + di * sf[j] + bb[j], 0.f);
        if (valid) {
            uint4 o;
            o.x = (unsigned)f2bf(vv[0]) | ((unsigned)f2bf(vv[1]) << 16);
            o.y = (unsigned)f2bf(vv[2]) | ((unsigned)f2bf(vv[3]) << 16);
            o.z = (unsigned)f2bf(vv[4]) | ((unsigned)f2bf(vv[5]) << 16);
            o.w = (unsigned)f2bf(vv[6]) | ((unsigned)f2bf(vv[7]) << 16);
            O4[(size_t)node * 8 + fq] = o;
#pragma unroll
            for (int j = 0; j < 8; j++) {
                ps1[j] += vv[j];
                ps2[j] += vv[j] * vv[j];
            }
        }
    }

    // colstats: reduce across the 8 groups (same fq -> same features), stage in LDS
    __shared__ float red[4][128];
    int wv = t >> 6;
#pragma unroll
    for (int j = 0; j < 8; j++) {
        float s = ps1[j], q = ps2[j];
        s += __shfl_xor(s, 8); s += __shfl_xor(s, 16); s += __shfl_xor(s, 32);
        q += __shfl_xor(q, 8); q += __shfl_xor(q, 16); q += __shfl_xor(q, 32);
        if (g == 0) {
            red[wv][fq * 8 + j] = s;
            red[wv][64 + fq * 8 + j] = q;
        }
    }
    __syncthreads();
    if (t < 128) {
        float v = red[0][t] + red[1][t] + red[2][t] + red[3][t];
        atomicAdd(&sums[t], v);
    }
}

// ---------- layer-2 norms + max-pool ----------

__device__ __forceinline__ float gn_ln_row(float x, float mean, float var, float ms, float gw,
                                           float gb, float lw, float lb) {
    float g = gw * (x - ms * mean) * rsqrtf(var + EPSV) + gb;
    float mu = g;
#pragma unroll
    for (int off = 32; off; off >>= 1) mu += __shfl_xor(mu, off);
    mu *= (1.f / 64.f);
    float c = g - mu;
    float vv = c * c;
#pragma unroll
    for (int off = 32; off; off >>= 1) vv += __shfl_xor(vv, off);
    vv *= (1.f / 64.f);
    return lw * c * rsqrtf(vv + EPSV) + lb;
}

__device__ __forceinline__ unsigned fkey(float f) {
    unsigned u = __float_as_uint(f);
    return (u & 0x80000000u) ? ~u : (u | 0x80000000u);
}

__global__ void gnlnmax_kernel(const ushort* __restrict__ A, const float* __restrict__ sums,
                               const float* __restrict__ gn_w, const float* __restrict__ gn_b,
                               const float* __restrict__ gn_ms, const float* __restrict__ ln_w,
                               const float* __restrict__ ln_b, unsigned* __restrict__ pooled,
                               int N) {
    __shared__ float lmax[256];
    int lane = threadIdx.x & 63;
    int wave0 = (blockIdx.x * blockDim.x + threadIdx.x) >> 6;
    int nw = (gridDim.x * blockDim.x) >> 6;
    float invN = 1.0f / (float)N;
    float mean = sums[lane] * invN;
    float m2 = sums[64 + lane] * invN;
    float ms = gn_ms[lane];
    float var = m2 - 2.f * ms * mean * mean + ms * ms * mean * mean;
    float gw = gn_w[lane], gb = gn_b[lane], lw = ln_w[lane], lb = ln_b[lane];
    float mx = -3.4e38f;
    for (int i = wave0; i < N; i += nw) {
        float y = gn_ln_row(bf2f(A[(size_t)i * 64 + lane]), mean, var, ms, gw, gb, lw, lb);
        mx = fmaxf(mx, y);
    }
    lmax[threadIdx.x] = mx;
    __syncthreads();
    if (threadIdx.x < 64) {
        float m = fmaxf(fmaxf(lmax[threadIdx.x], lmax[threadIdx.x + 64]),
                        fmaxf(lmax[threadIdx.x + 128], lmax[threadIdx.x + 192]));
        atomicMax(&pooled[threadIdx.x], fkey(m));
    }
}

// ---------- final FC ----------

__global__ void final_kernel(const unsigned* __restrict__ pooled, const float* __restrict__ fc_W,
                             const float* __restrict__ fc_b, float* __restrict__ out) {
    __shared__ float p[64];
    int t = threadIdx.x;
    if (t < 64) {
        unsigned u = pooled[t];
        p[t] = (u & 0x80000000u) ? __uint_as_float(u ^ 0x80000000u) : __uint_as_float(~u);
    }
    __syncthreads();
    if (t < 32) {
        float acc = fc_b[t];
#pragma unroll
        for (int f = 0; f < 64; f++) acc += p[f] * fc_W[f * 32 + t];
        out[t] = acc;
    }
}

// ---------- launch ----------

static inline size_t align_up(size_t v, size_t a) { return (v + a - 1) & ~(a - 1); }

extern "C" void kernel_launch(void* const* d_in, const int* in_sizes, int n_in, void* d_out,
                              int out_size, void* d_ws, size_t ws_size, hipStream_t stream) {
    const float* x = (const float*)d_in[0];
    const int* ei = (const int*)d_in[1];
    const float* W1 = (const float*)d_in[2];
    const float* b1 = (const float*)d_in[3];
    const float* W2 = (const float*)d_in[4];
    const float* b2 = (const float*)d_in[5];
    const float* gn_w = (const float*)d_in[6];
    const float* gn_b = (const float*)d_in[7];
    const float* gn_ms = (const float*)d_in[8];
    const float* ln_w = (const float*)d_in[9];
    const float* ln_b = (const float*)d_in[10];
    const float* fc_W = (const float*)d_in[11];
    const float* fc_b = (const float*)d_in[12];
    float* out = (float*)d_out;

    const int N = in_sizes[0] / 128;
    const int E = in_sizes[1] / 2;
    const int NB = (N + CHUNK - 1) / CHUNK;

    char* ws = (char*)d_ws;
    size_t off = 0;
    auto alloc = [&](size_t bytes) {
        char* p = ws + off;
        off = align_up(off + bytes, 256);
        return p;
    };
    int2* NI = (int2*)alloc((size_t)N * 8);
    int* bcur = (int*)alloc((size_t)(NB + 1) * 4);
    float* dinv = (float*)alloc((size_t)N * 4);
    unsigned* bdata = (unsigned*)alloc((size_t)NB * CAP * 4);
    int* srcs = (int*)alloc((size_t)NB * CAP * 4);
    ushort* bufB = (ushort*)alloc((size_t)N * 64 * 2);
    ushort* wsw1 = (ushort*)alloc(128 * 64 * 2);
    ushort* wsw2 = (ushort*)alloc(64 * 64 * 2);
    ushort* bufA = (ushort*)alloc((size_t)N * 64 * 2);  // gather source; zero row follows
    // ---- single contiguous zero-init region: [zrow][sums][pooled] ----
    size_t zoff = off;
    ushort* zrow = (ushort*)alloc(128);  // bufA row N (contiguous with bufA)
    float* sums = (float*)alloc(256 * 4);
    unsigned* pooled = (unsigned*)alloc(64 * 4);
    size_t zlen = off - zoff;
    (void)zrow;

    hipMemsetAsync(ws + zoff, 0, zlen, stream);

    // CSR build: fixed-capacity buckets (no global hist/scan passes)
    int nbB = (E + EPB - 1) / EPB;
    prep_kernel<<<48, 256, 0, stream>>>(W1, W2, wsw1, wsw2, bcur, NB);
    bucket_scatter<<<nbB, 256, 0, stream>>>(ei, bcur, bdata, E, NB);
    bucket_finish<<<NB, 256, 0, stream>>>(bdata, bcur, NI, dinv, srcs, N);

    int nbMM = (N + 63) / 64;
    int nbAgg = 782;  // ~4 node-octets per wave (balanced grid-stride)

    // Layer 1
    mm1_kernel<<<nbMM, 256, 0, stream>>>(x, wsw1, dinv, bufA, N);
    agg_kernel<<<nbAgg, 256, 0, stream>>>(bufA, NI, srcs, dinv, b1, bufB, sums, N);

    // Layer 2
    mm2_kernel<<<nbMM, 256, 0, stream>>>(bufB, wsw2, sums, gn_w, gn_b, gn_ms, ln_w, ln_b, dinv,
                                         bufA, N);
    agg_kernel<<<nbAgg, 256, 0, stream>>>(bufA, NI, srcs, dinv, b2, bufB, sums + 128, N);
    gnlnmax_kernel<<<512, 256, 0, stream>>>(bufB, sums + 128, gn_w, gn_b, gn_ms, ln_w, ln_b,
                                            pooled, N);

    final_kernel<<<1, 64, 0, stream>>>(pooled, fc_W, fc_b, out);
}